// Round 22
// baseline (554.106 us; speedup 1.0000x reference)
//
#include <hip/hip_runtime.h>
#include <hip/hip_bf16.h>
#include <stdint.h>

#define SEQ   2048
#define DIM   2048
#define HEADS 16
#define DHEAD 128
#define BATCH 4
#define MROWS (BATCH*SEQ)   // 8192

typedef short bf16x8 __attribute__((ext_vector_type(8)));
typedef float f32x4  __attribute__((ext_vector_type(4)));
typedef float f32x16 __attribute__((ext_vector_type(16)));
typedef unsigned short u16x8 __attribute__((ext_vector_type(8)));
typedef unsigned int u32x4 __attribute__((ext_vector_type(4)));
typedef short s16x4 __attribute__((ext_vector_type(4)));

__device__ __forceinline__ short f2bf(float f){
  union { float fv; unsigned u; } x; x.fv = f;
  unsigned r = x.u + 0x7fffu + ((x.u >> 16) & 1u);
  return (short)(r >> 16);
}

__device__ __forceinline__ unsigned cvtpk(float lo, float hi){
  unsigned r; asm("v_cvt_pk_bf16_f32 %0, %1, %2" : "=v"(r) : "v"(lo), "v"(hi)); return r;
}

__device__ __forceinline__ float exp2a(float x){
#if __has_builtin(__builtin_amdgcn_exp2f)
  return __builtin_amdgcn_exp2f(x);
#else
  return exp2f(x);
#endif
}

__device__ __forceinline__ void gl_lds16(const void* g, void* l){
  __builtin_amdgcn_global_load_lds((const __attribute__((address_space(1))) void*)g,
                                   (__attribute__((address_space(3))) void*)l, 16, 0, 0);
}

// Compiler + scheduler fence: pins issue order of surrounding VMEM ops so that
// counted s_waitcnt vmcnt(N) arithmetic is valid (issue order = retire order).
__device__ __forceinline__ void ofence(){
  asm volatile("" ::: "memory");
  __builtin_amdgcn_sched_barrier(0);
}

// ---------------- RMSNorm (fp32) + cast to bf16 ----------------
__global__ __launch_bounds__(256) void rmsnorm_cast_k(const float* __restrict__ tok,
                                                      const float* __restrict__ w,
                                                      short* __restrict__ x){
  const int row = blockIdx.x;
  const float4* r4 = (const float4*)(tok + (size_t)row * DIM);
  float4 a = r4[threadIdx.x * 2];
  float4 b = r4[threadIdx.x * 2 + 1];
  float ss = a.x*a.x + a.y*a.y + a.z*a.z + a.w*a.w
           + b.x*b.x + b.y*b.y + b.z*b.z + b.w*b.w;
  #pragma unroll
  for (int m = 1; m < 64; m <<= 1) ss += __shfl_xor(ss, m, 64);
  __shared__ float red[4];
  if ((threadIdx.x & 63) == 0) red[threadIdx.x >> 6] = ss;
  __syncthreads();
  float tot = red[0] + red[1] + red[2] + red[3];
  float rs = rsqrtf(tot * (1.0f / DIM) + 1.1920929e-07f);
  const float4* w4 = (const float4*)w;
  float4 wa = w4[threadIdx.x * 2];
  float4 wb = w4[threadIdx.x * 2 + 1];
  u16x8 o;
  o[0] = (unsigned short)f2bf(a.x * rs * wa.x);
  o[1] = (unsigned short)f2bf(a.y * rs * wa.y);
  o[2] = (unsigned short)f2bf(a.z * rs * wa.z);
  o[3] = (unsigned short)f2bf(a.w * rs * wa.w);
  o[4] = (unsigned short)f2bf(b.x * rs * wb.x);
  o[5] = (unsigned short)f2bf(b.y * rs * wb.y);
  o[6] = (unsigned short)f2bf(b.z * rs * wb.z);
  o[7] = (unsigned short)f2bf(b.w * rs * wb.w);
  *(u16x8*)(x + (size_t)row * DIM + threadIdx.x * 8) = o;
}

// ---------------- weight cast + transpose: w[K][N] fp32 -> wt[N][K] bf16 ----------------
__global__ __launch_bounds__(256) void wtrans_k(const float* __restrict__ w,
                                                short* __restrict__ wt,
                                                int K, int N){
  __shared__ float tile[64][65];
  const int r0 = blockIdx.y * 64;   // K direction
  const int c0 = blockIdx.x * 64;   // N direction
  const int t = threadIdx.x;
  #pragma unroll
  for (int i = 0; i < 4; i++){
    int e = i * 256 + t;            // 0..1023
    int r = e >> 4;                 // 0..63
    int c = (e & 15) * 4;           // 0..60
    float4 v = *(const float4*)&w[(size_t)(r0 + r) * N + c0 + c];
    tile[r][c]     = v.x;
    tile[r][c + 1] = v.y;
    tile[r][c + 2] = v.z;
    tile[r][c + 3] = v.w;
  }
  __syncthreads();
  #pragma unroll
  for (int i = 0; i < 16; i++){
    int e = i * 256 + t; int c = e >> 6, r = e & 63;
    wt[(size_t)(c0 + c) * K + r0 + r] = f2bf(tile[r][c]);
  }
}

// ---------------- V transpose: kv[b*S+n][4096] (v half) -> vt[(bh*128+d)][S] ----------------
__global__ __launch_bounds__(256) void vtrans_k(const short* __restrict__ kv,
                                                short* __restrict__ vt){
  __shared__ short tile[64][65];
  const int n0 = blockIdx.x * 64;
  const int d0 = blockIdx.y * 64;
  const int bh = blockIdx.z;
  const int b = bh >> 4, h = bh & 15;
  const int t = threadIdx.x;
  #pragma unroll
  for (int i = 0; i < 4; i++){
    int e = i * 256 + t;            // 0..1023
    int r = e >> 4;                 // n, 0..63
    int c = (e & 15) * 4;           // d, 0..60
    s16x4 v = *(const s16x4*)&kv[(size_t)(b * SEQ + n0 + r) * 4096 + 2048 + h * DHEAD + d0 + c];
    tile[r][c]     = v[0];
    tile[r][c + 1] = v[1];
    tile[r][c + 2] = v[2];
    tile[r][c + 3] = v[3];
  }
  __syncthreads();
  #pragma unroll
  for (int i = 0; i < 16; i++){
    int e = i * 256 + t; int c = e >> 6, r = e & 63;   // c = d, r = n
    vt[(size_t)(bh * DHEAD + d0 + c) * SEQ + n0 + r] = tile[r][c];
  }
}

// ---------------- 256x256 GEMM, BK=32, 4-slot ring, depth-3 prefetch, 2-phase stagger -----
__device__ __forceinline__ void storeC(float* C, size_t idx, float v){ C[idx] = v; }
__device__ __forceinline__ void storeC(short* C, size_t idx, float v){ C[idx] = f2bf(v); }

template<typename OutT>
__global__ __launch_bounds__(512, 2) void gemm256_k(const short* __restrict__ A,
                                                    const short* __restrict__ Bt,
                                                    OutT* __restrict__ C,
                                                    int M, int N, int K, int lgntn){
  __shared__ __align__(16) short As[4][256 * 32];
  __shared__ __align__(16) short Bs[4][256 * 32];
  const int nwg = gridDim.x;
  const int bid = blockIdx.x;
  const int o = (bid & 7) * (nwg >> 3) + (bid >> 3);   // XCD-contiguous remap (nwg%8==0)
  const int bm = o >> lgntn, bn = o & ((1 << lgntn) - 1);
  const int m0 = bm << 8, n0 = bn << 8;
  const int tid = threadIdx.x, lane = tid & 63, wid = tid >> 6;
  const int l31 = lane & 31, hi = lane >> 5;
  const int wr = wid >> 2, wc = wid & 3;
  const int NT = K >> 5;                                // K/32

  f32x16 acc[4][2] = {};

  auto stageA = [&](int t){
    const int slot = t & 3;
    const size_t kbase = (size_t)t << 5;
    #pragma unroll
    for (int i = 0; i < 2; i++){
      int c = i * 512 + tid;
      int row = c >> 2;
      int j = (c & 3) ^ ((row >> 1) & 3);
      gl_lds16(A + (size_t)(m0 + row) * K + kbase + j * 8,
               &As[slot][(i * 512 + wid * 64) * 8]);
    }
  };
  auto stageB = [&](int t){
    const int slot = t & 3;
    const size_t kbase = (size_t)t << 5;
    #pragma unroll
    for (int i = 0; i < 2; i++){
      int c = i * 512 + tid;
      int row = c >> 2;
      int j = (c & 3) ^ ((row >> 1) & 3);
      gl_lds16(Bt + (size_t)(n0 + row) * K + kbase + j * 8,
               &Bs[slot][(i * 512 + wid * 64) * 8]);
    }
  };

  stageA(0); stageB(0); ofence();
  stageA(1); stageB(1); ofence();
  stageA(2); stageB(2); ofence();                      // 12 loads in flight, order pinned
  asm volatile("s_waitcnt vmcnt(8)" ::: "memory");     // tile 0 (oldest 4) complete
  __builtin_amdgcn_s_barrier();

  for (int t = 0; t < NT; t++){
    const short* Ab = As[t & 3];
    const short* Bb = Bs[t & 3];

    // ---- Phase 1: B-frags + A-frags mb0,1; stage A(t+3); MFMA mb0,1 ----
    bf16x8 bfv[2][2], af0[2][2];
    #pragma unroll
    for (int nb = 0; nb < 2; nb++){
      int row = wc * 64 + nb * 32 + l31;
      #pragma unroll
      for (int ks = 0; ks < 2; ks++){
        int ch = (ks * 2 + hi) ^ ((row >> 1) & 3);
        bfv[nb][ks] = *(const bf16x8*)&Bb[row * 32 + ch * 8];
      }
    }
    #pragma unroll
    for (int mb = 0; mb < 2; mb++){
      int row = wr * 128 + mb * 32 + l31;
      #pragma unroll
      for (int ks = 0; ks < 2; ks++){
        int ch = (ks * 2 + hi) ^ ((row >> 1) & 3);
        af0[mb][ks] = *(const bf16x8*)&Ab[row * 32 + ch * 8];
      }
    }
    if (t + 3 < NT){ stageA(t + 3); ofence(); }
    __builtin_amdgcn_s_barrier();
    __builtin_amdgcn_s_setprio(1);
    #pragma unroll
    for (int mb = 0; mb < 2; mb++)
      #pragma unroll
      for (int nb = 0; nb < 2; nb++)
        #pragma unroll
        for (int ks = 0; ks < 2; ks++)
          acc[mb][nb] = __builtin_amdgcn_mfma_f32_32x32x16_bf16(af0[mb][ks], bfv[nb][ks],
                                                               acc[mb][nb], 0, 0, 0);
    __builtin_amdgcn_s_setprio(0);

    // ---- Phase 2: A-frags mb2,3; stage B(t+3); MFMA mb2,3; tile-end counted wait ----
    bf16x8 af1[2][2];
    #pragma unroll
    for (int mb = 0; mb < 2; mb++){
      int row = wr * 128 + (mb + 2) * 32 + l31;
      #pragma unroll
      for (int ks = 0; ks < 2; ks++){
        int ch = (ks * 2 + hi) ^ ((row >> 1) & 3);
        af1[mb][ks] = *(const bf16x8*)&Ab[row * 32 + ch * 8];
      }
    }
    if (t + 3 < NT){ stageB(t + 3); ofence(); }
    __builtin_amdgcn_s_barrier();
    __builtin_amdgcn_s_setprio(1);
    #pragma unroll
    for (int mb = 0; mb < 2; mb++)
      #pragma unroll
      for (int nb = 0; nb < 2; nb++)
        #pragma unroll
        for (int ks = 0; ks < 2; ks++)
          acc[mb + 2][nb] = __builtin_amdgcn_mfma_f32_32x32x16_bf16(af1[mb][ks], bfv[nb][ks],
                                                                   acc[mb + 2][nb], 0, 0, 0);
    __builtin_amdgcn_s_setprio(0);

    if (t + 1 < NT){
      if (t + 3 < NT)      asm volatile("s_waitcnt vmcnt(8)" ::: "memory");
      else if (t + 2 < NT) asm volatile("s_waitcnt vmcnt(4)" ::: "memory");
      else                 asm volatile("s_waitcnt vmcnt(0)" ::: "memory");
      __builtin_amdgcn_s_barrier();
    }
  }

  #pragma unroll
  for (int mb = 0; mb < 4; mb++)
    #pragma unroll
    for (int nb = 0; nb < 2; nb++)
      #pragma unroll
      for (int reg = 0; reg < 16; reg++){
        int r = (reg & 3) + 8 * (reg >> 2) + 4 * hi;
        int row = m0 + wr * 128 + mb * 32 + r;
        int col = n0 + wc * 64 + nb * 32 + l31;
        storeC(C, (size_t)row * N + col, acc[mb][nb][reg]);
      }
}

// ---------------- Flash attention: 48 KiB LDS (K single-buffer, V double-buffer) -----------
// R20-exact (passing, 217 us). Schedule: 2 barriers/iter, exact vmcnt invariant:
//   outstanding at iter top is always {K(kt), V(kt)} = 8 loads.
//   top: vmcnt(4) -> K(kt) landed; barrier. QK.
//   mid: vmcnt(0)+lgkmcnt(0) -> V(kt) landed, Ks reads consumed; barrier -> WAR-clear.
//   stage K(kt+1)->Ks, V(kt+1)->Vts[cur^1]; softmax; PV from Vts[cur]. No end barrier.
// PV P-redistribution via v_permlane32_swap_b32 (T12, R20-proven).
// NOTE: softmax body is codegen-brittle (counted vmcnt) — do not perturb (R13/R14/R21).
__global__ __launch_bounds__(256) void attn_k(const short* __restrict__ q,
                                              const short* __restrict__ kv,
                                              const short* __restrict__ vt,
                                              short* __restrict__ out){
  __shared__ __align__(16) short Ks[64 * 128];
  __shared__ __align__(16) short Vts[2][128 * 64];
  const int bid = blockIdx.x, nb = gridDim.x;           // 1024 = 64 bh x 16 qt
  const int o = (bid & 7) * (nb >> 3) + (bid >> 3);     // XCD-contiguous (nb%8==0)
  const int qt = o & 15, bh = o >> 4;
  const int b = bh >> 4, h = bh & 15;
  const int tid = threadIdx.x, lane = tid & 63, wid = tid >> 6;
  const int l31 = lane & 31, hi = lane >> 5;
  const int qrow0 = qt * 128 + wid * 32;
  const float c2 = 0.08838834764831845f * 1.4426950408889634f;  // (1/sqrt(128)) * log2(e)
  const int NT = SEQ / 64;

  bf16x8 qf[8];
  {
    const short* qp = q + (size_t)(b * SEQ + qrow0 + l31) * DIM + h * DHEAD + hi * 8;
    #pragma unroll
    for (int s = 0; s < 8; s++) qf[s] = *(const bf16x8*)(qp + s * 16);
  }
  asm volatile("s_waitcnt vmcnt(0)" ::: "memory");  // qf resident: vmcnt domain = staging only
  ofence();

  f32x16 acc[4] = {};
  float m2 = -3e38f, l_s = 0.f;

  auto stage_K = [&](int kt){
    #pragma unroll
    for (int i = 0; i < 4; i++){
      int cb = (i * 4 + wid) * 64;
      int c  = cb + lane;
      int kr = c >> 4, kj = (c & 15) ^ (kr & 15);        // K: 4-bit chunk swizzle
      gl_lds16(kv + (size_t)(b * SEQ + kt * 64 + kr) * 4096 + h * DHEAD + kj * 8,
               &Ks[cb * 8]);
    }
  };
  auto stage_V = [&](int kt, int bs){
    #pragma unroll
    for (int i = 0; i < 4; i++){
      int cb = (i * 4 + wid) * 64;
      int c  = cb + lane;
      int vr = c >> 3, vj = (c & 7) ^ (vr & 7);          // V: 3-bit (8-chunk rows)
      gl_lds16(vt + (size_t)(bh * DHEAD + vr) * SEQ + kt * 64 + vj * 8,
               &Vts[bs][cb * 8]);
    }
  };

  stage_K(0); ofence();
  stage_V(0, 0); ofence();                              // outstanding: K0(4) V0(4)

  for (int kt = 0; kt < NT; kt++){
    const int cur = kt & 1;

    // ---- top: K(kt) landed ({K,V}=8 outstanding -> retire oldest 4) ----
    asm volatile("s_waitcnt vmcnt(4)" ::: "memory");
    __builtin_amdgcn_s_barrier();

    // ---- QK^T (swapped) from Ks ----
    f32x16 t0 = {0,0,0,0,0,0,0,0,0,0,0,0,0,0,0,0};
    f32x16 t1 = t0;
    {
      const int r0 = l31, r1 = l31 + 32;
      #pragma unroll
      for (int s = 0; s < 8; s++){
        bf16x8 k0 = *(const bf16x8*)&Ks[r0 * 128 + (((2 * s + hi) ^ (r0 & 15)) * 8)];
        bf16x8 k1 = *(const bf16x8*)&Ks[r1 * 128 + (((2 * s + hi) ^ (r1 & 15)) * 8)];
        t0 = __builtin_amdgcn_mfma_f32_32x32x16_bf16(k0, qf[s], t0, 0, 0, 0);
        t1 = __builtin_amdgcn_mfma_f32_32x32x16_bf16(k1, qf[s], t1, 0, 0, 0);
      }
    }

    // ---- mid: V(kt) landed + Ks reads consumed; then re-stage into Ks / Vts[cur^1] ----
    asm volatile("s_waitcnt vmcnt(0) lgkmcnt(0)" ::: "memory");
    __builtin_amdgcn_s_barrier();
    if (kt + 1 < NT){
      stage_K(kt + 1); ofence();
      stage_V(kt + 1, cur ^ 1); ofence();
    }

    // ---- softmax (defer-max, exp2 domain) ----
    float mxr = t0[0];
    #pragma unroll
    for (int i = 1; i < 16; i++) mxr = fmaxf(mxr, t0[i]);
    #pragma unroll
    for (int i = 0; i < 16; i++) mxr = fmaxf(mxr, t1[i]);
    mxr = fmaxf(mxr, __shfl_xor(mxr, 32));
    float mx2 = mxr * c2;
    if (!__all(mx2 <= m2 + 11.5f)){
      float m2n = fmaxf(m2, mx2);
      float al = exp2a(m2 - m2n);
      m2 = m2n;
      l_s *= al;
      #pragma unroll
      for (int reg = 0; reg < 16; reg++){
        float ar = __shfl(al, (reg & 3) + 8 * (reg >> 2) + 4 * hi);
        #pragma unroll
        for (int dt = 0; dt < 4; dt++) acc[dt][reg] *= ar;
      }
    }

    float ps = 0.f;
    unsigned w[16];
    #pragma unroll
    for (int pr = 0; pr < 8; pr++){
      float pa_ = exp2a(fmaf(t0[2 * pr], c2, -m2));
      float pb_ = exp2a(fmaf(t0[2 * pr + 1], c2, -m2));
      ps += pa_ + pb_;
      w[pr] = cvtpk(pa_, pb_);
    }
    #pragma unroll
    for (int pr = 0; pr < 8; pr++){
      float pa_ = exp2a(fmaf(t1[2 * pr], c2, -m2));
      float pb_ = exp2a(fmaf(t1[2 * pr + 1], c2, -m2));
      ps += pa_ + pb_;
      w[8 + pr] = cvtpk(pa_, pb_);
    }
    ps += __shfl_xor(ps, 32);
    l_s += ps;

    // ---- PV from Vts[cur]: P-redistribution via permlane32_swap (T12) ----
    const short* Vb = Vts[cur];
    #pragma unroll
    for (int fp = 0; fp < 4; fp++){
      unsigned f0 = w[fp * 4 + 0], f2 = w[fp * 4 + 2];
      unsigned f1 = w[fp * 4 + 1], f3 = w[fp * 4 + 3];
      asm("v_permlane32_swap_b32 %0, %1" : "+v"(f0), "+v"(f2));
      asm("v_permlane32_swap_b32 %0, %1" : "+v"(f1), "+v"(f3));
      u32x4 fw;
      fw[0] = f0;
      fw[1] = f1;
      fw[2] = f2;
      fw[3] = f3;
      union { u32x4 u; bf16x8 v; } pc; pc.u = fw;
      #pragma unroll
      for (int dt = 0; dt < 4; dt++){
        int vr = dt * 32 + l31;
        bf16x8 vb = *(const bf16x8*)&Vb[vr * 64 + (((2 * fp + hi) ^ (vr & 7)) * 8)];
        acc[dt] = __builtin_amdgcn_mfma_f32_32x32x16_bf16(pc.v, vb, acc[dt], 0, 0, 0);
      }
    }
  }

  float inv = 1.0f / l_s;
  #pragma unroll
  for (int reg = 0; reg < 16; reg++){
    int cr = (reg & 3) + 8 * (reg >> 2) + 4 * hi;
    float li = __shfl(inv, cr);
    int row = qrow0 + cr;
    #pragma unroll
    for (int dt = 0; dt < 4; dt++)
      out[(size_t)(b * SEQ + row) * DIM + h * DHEAD + dt * 32 + l31] = f2bf(acc[dt][reg] * li);
  }
}

// ---------------- launch ----------------
extern "C" void kernel_launch(void* const* d_in, const int* in_sizes, int n_in,
                              void* d_out, int out_size, void* d_ws, size_t ws_size,
                              hipStream_t stream) {
  (void)in_sizes; (void)n_in; (void)out_size; (void)ws_size;
  const float* tokens = (const float*)d_in[0];
  const float* normw  = (const float*)d_in[1];
  const float* wq     = (const float*)d_in[2];
  const float* wkv    = (const float*)d_in[3];
  const float* wout   = (const float*)d_in[4];
  float* outp = (float*)d_out;
  char* ws = (char*)d_ws;

  short* x     = (short*)(ws + 0);                    // 8192*2048*2   = 33554432
  short* wqt   = (short*)(ws + 33554432);             // 2048*2048*2   = 8388608
  short* wkvt  = (short*)(ws + 41943040);             // 4096*2048*2   = 16777216
  short* woutt = (short*)(ws + 58720256);             // 2048*2048*2   = 8388608
  short* qb    = (short*)(ws + 67108864);             // 8192*2048*2   = 33554432 (also attn out)
  short* kvb   = (short*)(ws + 100663296);            // 8192*4096*2   = 67108864
  short* vtb   = (short*)(ws + 167772160);            // 64*128*2048*2 = 33554432  (end 201326592)

  rmsnorm_cast_k<<<dim3(MROWS), dim3(256), 0, stream>>>(tokens, normw, x);
  wtrans_k<<<dim3(2048/64, 2048/64), dim3(256), 0, stream>>>(wq,   wqt,   2048, 2048);
  wtrans_k<<<dim3(4096/64, 2048/64), dim3(256), 0, stream>>>(wkv,  wkvt,  2048, 4096);
  wtrans_k<<<dim3(2048/64, 2048/64), dim3(256), 0, stream>>>(wout, woutt, 2048, 2048);
  gemm256_k<short><<<dim3((MROWS/256)*(2048/256)), dim3(512), 0, stream>>>(x, wqt,  qb,  MROWS, 2048, 2048, 3);
  gemm256_k<short><<<dim3((MROWS/256)*(4096/256)), dim3(512), 0, stream>>>(x, wkvt, kvb, MROWS, 4096, 2048, 4);
  vtrans_k<<<dim3(SEQ/64, DHEAD/64, BATCH*HEADS), dim3(256), 0, stream>>>(kvb, vtb);
  attn_k<<<dim3(SEQ/128 * BATCH*HEADS), dim3(256), 0, stream>>>(qb, kvb, vtb, qb);
  gemm256_k<float><<<dim3((MROWS/256)*(2048/256)), dim3(512), 0, stream>>>(qb, woutt, outp, MROWS, 2048, 2048, 3);
}

// Round 23
// 537.763 us; speedup vs baseline: 1.0304x; 1.0304x over previous
//
#include <hip/hip_runtime.h>
#include <hip/hip_bf16.h>
#include <stdint.h>

#define SEQ   2048
#define DIM   2048
#define HEADS 16
#define DHEAD 128
#define BATCH 4
#define MROWS (BATCH*SEQ)   // 8192

typedef short bf16x8 __attribute__((ext_vector_type(8)));
typedef float f32x4  __attribute__((ext_vector_type(4)));
typedef float f32x16 __attribute__((ext_vector_type(16)));
typedef unsigned short u16x8 __attribute__((ext_vector_type(8)));
typedef unsigned int u32x4 __attribute__((ext_vector_type(4)));
typedef unsigned int u32x2 __attribute__((ext_vector_type(2)));
typedef short s16x4 __attribute__((ext_vector_type(4)));

__device__ __forceinline__ short f2bf(float f){
  union { float fv; unsigned u; } x; x.fv = f;
  unsigned r = x.u + 0x7fffu + ((x.u >> 16) & 1u);
  return (short)(r >> 16);
}

__device__ __forceinline__ unsigned cvtpk(float lo, float hi){
  unsigned r; asm("v_cvt_pk_bf16_f32 %0, %1, %2" : "=v"(r) : "v"(lo), "v"(hi)); return r;
}

__device__ __forceinline__ float exp2a(float x){
#if __has_builtin(__builtin_amdgcn_exp2f)
  return __builtin_amdgcn_exp2f(x);
#else
  return exp2f(x);
#endif
}

__device__ __forceinline__ void gl_lds16(const void* g, void* l){
  __builtin_amdgcn_global_load_lds((const __attribute__((address_space(1))) void*)g,
                                   (__attribute__((address_space(3))) void*)l, 16, 0, 0);
}

// Compiler + scheduler fence: pins issue order of surrounding VMEM ops so that
// counted s_waitcnt vmcnt(N) arithmetic is valid (issue order = retire order).
__device__ __forceinline__ void ofence(){
  asm volatile("" ::: "memory");
  __builtin_amdgcn_sched_barrier(0);
}

// ---------------- RMSNorm (fp32) + cast to bf16 ----------------
__global__ __launch_bounds__(256) void rmsnorm_cast_k(const float* __restrict__ tok,
                                                      const float* __restrict__ w,
                                                      short* __restrict__ x){
  const int row = blockIdx.x;
  const float4* r4 = (const float4*)(tok + (size_t)row * DIM);
  float4 a = r4[threadIdx.x * 2];
  float4 b = r4[threadIdx.x * 2 + 1];
  float ss = a.x*a.x + a.y*a.y + a.z*a.z + a.w*a.w
           + b.x*b.x + b.y*b.y + b.z*b.z + b.w*b.w;
  #pragma unroll
  for (int m = 1; m < 64; m <<= 1) ss += __shfl_xor(ss, m, 64);
  __shared__ float red[4];
  if ((threadIdx.x & 63) == 0) red[threadIdx.x >> 6] = ss;
  __syncthreads();
  float tot = red[0] + red[1] + red[2] + red[3];
  float rs = rsqrtf(tot * (1.0f / DIM) + 1.1920929e-07f);
  const float4* w4 = (const float4*)w;
  float4 wa = w4[threadIdx.x * 2];
  float4 wb = w4[threadIdx.x * 2 + 1];
  u16x8 o;
  o[0] = (unsigned short)f2bf(a.x * rs * wa.x);
  o[1] = (unsigned short)f2bf(a.y * rs * wa.y);
  o[2] = (unsigned short)f2bf(a.z * rs * wa.z);
  o[3] = (unsigned short)f2bf(a.w * rs * wa.w);
  o[4] = (unsigned short)f2bf(b.x * rs * wb.x);
  o[5] = (unsigned short)f2bf(b.y * rs * wb.y);
  o[6] = (unsigned short)f2bf(b.z * rs * wb.z);
  o[7] = (unsigned short)f2bf(b.w * rs * wb.w);
  *(u16x8*)(x + (size_t)row * DIM + threadIdx.x * 8) = o;
}

// ---------------- weight cast + transpose: w[K][N] fp32 -> wt[N][K] bf16 ----------------
__global__ __launch_bounds__(256) void wtrans_k(const float* __restrict__ w,
                                                short* __restrict__ wt,
                                                int K, int N){
  __shared__ float tile[64][65];
  const int r0 = blockIdx.y * 64;   // K direction
  const int c0 = blockIdx.x * 64;   // N direction
  const int t = threadIdx.x;
  #pragma unroll
  for (int i = 0; i < 4; i++){
    int e = i * 256 + t;            // 0..1023
    int r = e >> 4;                 // 0..63
    int c = (e & 15) * 4;           // 0..60
    float4 v = *(const float4*)&w[(size_t)(r0 + r) * N + c0 + c];
    tile[r][c]     = v.x;
    tile[r][c + 1] = v.y;
    tile[r][c + 2] = v.z;
    tile[r][c + 3] = v.w;
  }
  __syncthreads();
  #pragma unroll
  for (int i = 0; i < 16; i++){
    int e = i * 256 + t; int c = e >> 6, r = e & 63;
    wt[(size_t)(c0 + c) * K + r0 + r] = f2bf(tile[r][c]);
  }
}

// ---------------- 256x256 GEMM, BK=32, 4-slot ring, depth-3 prefetch, 2-phase stagger -----
// MODE 0: normal C write. MODE 1 (KV GEMM): blocks with n0 >= 2048 hold the V-half; their
// 256x256 tile is written TRANSPOSED to VT ([(b*2048+d_rel)][SEQ]) via a per-wave-private
// 8 KB LDS bounce (reuses As, dead after the K-loop; one uniform barrier guards WAR).
// This replaces the former vtrans_k pass (saves 67 MB of traffic + a dispatch).
__device__ __forceinline__ void storeC(float* C, size_t idx, float v){ C[idx] = v; }
__device__ __forceinline__ void storeC(short* C, size_t idx, float v){ C[idx] = f2bf(v); }

template<typename OutT, int MODE>
__global__ __launch_bounds__(512, 2) void gemm256_k(const short* __restrict__ A,
                                                    const short* __restrict__ Bt,
                                                    OutT* __restrict__ C,
                                                    short* __restrict__ VT,
                                                    int M, int N, int K, int lgntn){
  __shared__ __align__(16) short As[4][256 * 32];
  __shared__ __align__(16) short Bs[4][256 * 32];
  const int nwg = gridDim.x;
  const int bid = blockIdx.x;
  const int o = (bid & 7) * (nwg >> 3) + (bid >> 3);   // XCD-contiguous remap (nwg%8==0)
  const int bm = o >> lgntn, bn = o & ((1 << lgntn) - 1);
  const int m0 = bm << 8, n0 = bn << 8;
  const int tid = threadIdx.x, lane = tid & 63, wid = tid >> 6;
  const int l31 = lane & 31, hi = lane >> 5;
  const int wr = wid >> 2, wc = wid & 3;
  const int NT = K >> 5;                                // K/32

  f32x16 acc[4][2] = {};

  auto stageA = [&](int t){
    const int slot = t & 3;
    const size_t kbase = (size_t)t << 5;
    #pragma unroll
    for (int i = 0; i < 2; i++){
      int c = i * 512 + tid;
      int row = c >> 2;
      int j = (c & 3) ^ ((row >> 1) & 3);
      gl_lds16(A + (size_t)(m0 + row) * K + kbase + j * 8,
               &As[slot][(i * 512 + wid * 64) * 8]);
    }
  };
  auto stageB = [&](int t){
    const int slot = t & 3;
    const size_t kbase = (size_t)t << 5;
    #pragma unroll
    for (int i = 0; i < 2; i++){
      int c = i * 512 + tid;
      int row = c >> 2;
      int j = (c & 3) ^ ((row >> 1) & 3);
      gl_lds16(Bt + (size_t)(n0 + row) * K + kbase + j * 8,
               &Bs[slot][(i * 512 + wid * 64) * 8]);
    }
  };

  stageA(0); stageB(0); ofence();
  stageA(1); stageB(1); ofence();
  stageA(2); stageB(2); ofence();                      // 12 loads in flight, order pinned
  asm volatile("s_waitcnt vmcnt(8)" ::: "memory");     // tile 0 (oldest 4) complete
  __builtin_amdgcn_s_barrier();

  for (int t = 0; t < NT; t++){
    const short* Ab = As[t & 3];
    const short* Bb = Bs[t & 3];

    // ---- Phase 1: B-frags + A-frags mb0,1; stage A(t+3); MFMA mb0,1 ----
    bf16x8 bfv[2][2], af0[2][2];
    #pragma unroll
    for (int nb = 0; nb < 2; nb++){
      int row = wc * 64 + nb * 32 + l31;
      #pragma unroll
      for (int ks = 0; ks < 2; ks++){
        int ch = (ks * 2 + hi) ^ ((row >> 1) & 3);
        bfv[nb][ks] = *(const bf16x8*)&Bb[row * 32 + ch * 8];
      }
    }
    #pragma unroll
    for (int mb = 0; mb < 2; mb++){
      int row = wr * 128 + mb * 32 + l31;
      #pragma unroll
      for (int ks = 0; ks < 2; ks++){
        int ch = (ks * 2 + hi) ^ ((row >> 1) & 3);
        af0[mb][ks] = *(const bf16x8*)&Ab[row * 32 + ch * 8];
      }
    }
    if (t + 3 < NT){ stageA(t + 3); ofence(); }
    __builtin_amdgcn_s_barrier();
    __builtin_amdgcn_s_setprio(1);
    #pragma unroll
    for (int mb = 0; mb < 2; mb++)
      #pragma unroll
      for (int nb = 0; nb < 2; nb++)
        #pragma unroll
        for (int ks = 0; ks < 2; ks++)
          acc[mb][nb] = __builtin_amdgcn_mfma_f32_32x32x16_bf16(af0[mb][ks], bfv[nb][ks],
                                                               acc[mb][nb], 0, 0, 0);
    __builtin_amdgcn_s_setprio(0);

    // ---- Phase 2: A-frags mb2,3; stage B(t+3); MFMA mb2,3; tile-end counted wait ----
    bf16x8 af1[2][2];
    #pragma unroll
    for (int mb = 0; mb < 2; mb++){
      int row = wr * 128 + (mb + 2) * 32 + l31;
      #pragma unroll
      for (int ks = 0; ks < 2; ks++){
        int ch = (ks * 2 + hi) ^ ((row >> 1) & 3);
        af1[mb][ks] = *(const bf16x8*)&Ab[row * 32 + ch * 8];
      }
    }
    if (t + 3 < NT){ stageB(t + 3); ofence(); }
    __builtin_amdgcn_s_barrier();
    __builtin_amdgcn_s_setprio(1);
    #pragma unroll
    for (int mb = 0; mb < 2; mb++)
      #pragma unroll
      for (int nb = 0; nb < 2; nb++)
        #pragma unroll
        for (int ks = 0; ks < 2; ks++)
          acc[mb + 2][nb] = __builtin_amdgcn_mfma_f32_32x32x16_bf16(af1[mb][ks], bfv[nb][ks],
                                                                   acc[mb + 2][nb], 0, 0, 0);
    __builtin_amdgcn_s_setprio(0);

    if (t + 1 < NT){
      if (t + 3 < NT)      asm volatile("s_waitcnt vmcnt(8)" ::: "memory");
      else if (t + 2 < NT) asm volatile("s_waitcnt vmcnt(4)" ::: "memory");
      else                 asm volatile("s_waitcnt vmcnt(0)" ::: "memory");
      __builtin_amdgcn_s_barrier();
    }
  }

  if constexpr (MODE == 1){
    if (n0 >= 2048){
      // ---- transposed epilogue: tile -> VT[(b*2048+d_rel)][SEQ] via per-wave LDS bounce ----
      asm volatile("s_waitcnt lgkmcnt(0)" ::: "memory");
      __builtin_amdgcn_s_barrier();                    // all waves done reading As/Bs
      short* scr = &As[0][0] + wid * 4096;             // 64x64 shorts, per-wave private
      const int drel0 = (n0 - 2048) + wc * 64;
      #pragma unroll
      for (int h0 = 0; h0 < 2; h0++){
        // write phase: scr[col][row ^ swz] (transpose-on-write, 4-row b64 packs)
        #pragma unroll
        for (int mbl = 0; mbl < 2; mbl++){
          #pragma unroll
          for (int nb = 0; nb < 2; nb++){
            int colL = nb * 32 + l31;
            int swz = (colL & 7) << 3;
            #pragma unroll
            for (int qq = 0; qq < 4; qq++){
              int rowL = mbl * 32 + 8 * qq + 4 * hi;
              u32x2 pk;
              pk[0] = cvtpk(acc[h0*2+mbl][nb][4*qq+0], acc[h0*2+mbl][nb][4*qq+1]);
              pk[1] = cvtpk(acc[h0*2+mbl][nb][4*qq+2], acc[h0*2+mbl][nb][4*qq+3]);
              *(u32x2*)(scr + colL * 64 + (rowL ^ swz)) = pk;
            }
          }
        }
        asm volatile("s_waitcnt lgkmcnt(0)" ::: "memory");   // wave-local writes visible
        // read phase: lane owns d-column dL; 8 x b128 contiguous rows -> coalesced-per-lane store
        int dL = lane;
        int d_rel = drel0 + dL;
        int rowg0 = m0 + wr * 128 + h0 * 64;
        int bb = rowg0 >> 11, nn2 = rowg0 & 2047;
        short* dst = VT + ((size_t)bb * 2048 + d_rel) * SEQ + nn2;
        int rsw = (dL & 7) << 3;
        #pragma unroll
        for (int ch = 0; ch < 8; ch++){
          bf16x8 v = *(const bf16x8*)(scr + dL * 64 + ((ch * 8) ^ rsw));
          *(bf16x8*)(dst + ch * 8) = v;
        }
        if (h0 == 0) asm volatile("s_waitcnt lgkmcnt(0)" ::: "memory");  // reads done before rewrite
      }
      return;
    }
  }

  #pragma unroll
  for (int mb = 0; mb < 4; mb++)
    #pragma unroll
    for (int nb = 0; nb < 2; nb++)
      #pragma unroll
      for (int reg = 0; reg < 16; reg++){
        int r = (reg & 3) + 8 * (reg >> 2) + 4 * hi;
        int row = m0 + wr * 128 + mb * 32 + r;
        int col = n0 + wc * 64 + nb * 32 + l31;
        storeC(C, (size_t)row * N + col, acc[mb][nb][reg]);
      }
}

// ---------------- Flash attention: 48 KiB LDS (K single-buffer, V double-buffer) -----------
// R20-exact (passing, 217 us). Schedule: 2 barriers/iter, exact vmcnt invariant:
//   outstanding at iter top is always {K(kt), V(kt)} = 8 loads.
//   top: vmcnt(4) -> K(kt) landed; barrier. QK.
//   mid: vmcnt(0)+lgkmcnt(0) -> V(kt) landed, Ks reads consumed; barrier -> WAR-clear.
//   stage K(kt+1)->Ks, V(kt+1)->Vts[cur^1]; softmax; PV from Vts[cur]. No end barrier.
// PV P-redistribution via v_permlane32_swap_b32 (T12, R20-proven).
// NOTE: softmax body is codegen-brittle (counted vmcnt) — do not perturb (R13/R14/R21).
__global__ __launch_bounds__(256) void attn_k(const short* __restrict__ q,
                                              const short* __restrict__ kv,
                                              const short* __restrict__ vt,
                                              short* __restrict__ out){
  __shared__ __align__(16) short Ks[64 * 128];
  __shared__ __align__(16) short Vts[2][128 * 64];
  const int bid = blockIdx.x, nb = gridDim.x;           // 1024 = 64 bh x 16 qt
  const int o = (bid & 7) * (nb >> 3) + (bid >> 3);     // XCD-contiguous (nb%8==0)
  const int qt = o & 15, bh = o >> 4;
  const int b = bh >> 4, h = bh & 15;
  const int tid = threadIdx.x, lane = tid & 63, wid = tid >> 6;
  const int l31 = lane & 31, hi = lane >> 5;
  const int qrow0 = qt * 128 + wid * 32;
  const float c2 = 0.08838834764831845f * 1.4426950408889634f;  // (1/sqrt(128)) * log2(e)
  const int NT = SEQ / 64;

  bf16x8 qf[8];
  {
    const short* qp = q + (size_t)(b * SEQ + qrow0 + l31) * DIM + h * DHEAD + hi * 8;
    #pragma unroll
    for (int s = 0; s < 8; s++) qf[s] = *(const bf16x8*)(qp + s * 16);
  }
  asm volatile("s_waitcnt vmcnt(0)" ::: "memory");  // qf resident: vmcnt domain = staging only
  ofence();

  f32x16 acc[4] = {};
  float m2 = -3e38f, l_s = 0.f;

  auto stage_K = [&](int kt){
    #pragma unroll
    for (int i = 0; i < 4; i++){
      int cb = (i * 4 + wid) * 64;
      int c  = cb + lane;
      int kr = c >> 4, kj = (c & 15) ^ (kr & 15);        // K: 4-bit chunk swizzle
      gl_lds16(kv + (size_t)(b * SEQ + kt * 64 + kr) * 4096 + h * DHEAD + kj * 8,
               &Ks[cb * 8]);
    }
  };
  auto stage_V = [&](int kt, int bs){
    #pragma unroll
    for (int i = 0; i < 4; i++){
      int cb = (i * 4 + wid) * 64;
      int c  = cb + lane;
      int vr = c >> 3, vj = (c & 7) ^ (vr & 7);          // V: 3-bit (8-chunk rows)
      gl_lds16(vt + (size_t)(bh * DHEAD + vr) * SEQ + kt * 64 + vj * 8,
               &Vts[bs][cb * 8]);
    }
  };

  stage_K(0); ofence();
  stage_V(0, 0); ofence();                              // outstanding: K0(4) V0(4)

  for (int kt = 0; kt < NT; kt++){
    const int cur = kt & 1;

    // ---- top: K(kt) landed ({K,V}=8 outstanding -> retire oldest 4) ----
    asm volatile("s_waitcnt vmcnt(4)" ::: "memory");
    __builtin_amdgcn_s_barrier();

    // ---- QK^T (swapped) from Ks ----
    f32x16 t0 = {0,0,0,0,0,0,0,0,0,0,0,0,0,0,0,0};
    f32x16 t1 = t0;
    {
      const int r0 = l31, r1 = l31 + 32;
      #pragma unroll
      for (int s = 0; s < 8; s++){
        bf16x8 k0 = *(const bf16x8*)&Ks[r0 * 128 + (((2 * s + hi) ^ (r0 & 15)) * 8)];
        bf16x8 k1 = *(const bf16x8*)&Ks[r1 * 128 + (((2 * s + hi) ^ (r1 & 15)) * 8)];
        t0 = __builtin_amdgcn_mfma_f32_32x32x16_bf16(k0, qf[s], t0, 0, 0, 0);
        t1 = __builtin_amdgcn_mfma_f32_32x32x16_bf16(k1, qf[s], t1, 0, 0, 0);
      }
    }

    // ---- mid: V(kt) landed + Ks reads consumed; then re-stage into Ks / Vts[cur^1] ----
    asm volatile("s_waitcnt vmcnt(0) lgkmcnt(0)" ::: "memory");
    __builtin_amdgcn_s_barrier();
    if (kt + 1 < NT){
      stage_K(kt + 1); ofence();
      stage_V(kt + 1, cur ^ 1); ofence();
    }

    // ---- softmax (defer-max, exp2 domain) ----
    float mxr = t0[0];
    #pragma unroll
    for (int i = 1; i < 16; i++) mxr = fmaxf(mxr, t0[i]);
    #pragma unroll
    for (int i = 0; i < 16; i++) mxr = fmaxf(mxr, t1[i]);
    mxr = fmaxf(mxr, __shfl_xor(mxr, 32));
    float mx2 = mxr * c2;
    if (!__all(mx2 <= m2 + 11.5f)){
      float m2n = fmaxf(m2, mx2);
      float al = exp2a(m2 - m2n);
      m2 = m2n;
      l_s *= al;
      #pragma unroll
      for (int reg = 0; reg < 16; reg++){
        float ar = __shfl(al, (reg & 3) + 8 * (reg >> 2) + 4 * hi);
        #pragma unroll
        for (int dt = 0; dt < 4; dt++) acc[dt][reg] *= ar;
      }
    }

    float ps = 0.f;
    unsigned w[16];
    #pragma unroll
    for (int pr = 0; pr < 8; pr++){
      float pa_ = exp2a(fmaf(t0[2 * pr], c2, -m2));
      float pb_ = exp2a(fmaf(t0[2 * pr + 1], c2, -m2));
      ps += pa_ + pb_;
      w[pr] = cvtpk(pa_, pb_);
    }
    #pragma unroll
    for (int pr = 0; pr < 8; pr++){
      float pa_ = exp2a(fmaf(t1[2 * pr], c2, -m2));
      float pb_ = exp2a(fmaf(t1[2 * pr + 1], c2, -m2));
      ps += pa_ + pb_;
      w[8 + pr] = cvtpk(pa_, pb_);
    }
    ps += __shfl_xor(ps, 32);
    l_s += ps;

    // ---- PV from Vts[cur]: P-redistribution via permlane32_swap (T12) ----
    const short* Vb = Vts[cur];
    #pragma unroll
    for (int fp = 0; fp < 4; fp++){
      unsigned f0 = w[fp * 4 + 0], f2 = w[fp * 4 + 2];
      unsigned f1 = w[fp * 4 + 1], f3 = w[fp * 4 + 3];
      asm("v_permlane32_swap_b32 %0, %1" : "+v"(f0), "+v"(f2));
      asm("v_permlane32_swap_b32 %0, %1" : "+v"(f1), "+v"(f3));
      u32x4 fw;
      fw[0] = f0;
      fw[1] = f1;
      fw[2] = f2;
      fw[3] = f3;
      union { u32x4 u; bf16x8 v; } pc; pc.u = fw;
      #pragma unroll
      for (int dt = 0; dt < 4; dt++){
        int vr = dt * 32 + l31;
        bf16x8 vb = *(const bf16x8*)&Vb[vr * 64 + (((2 * fp + hi) ^ (vr & 7)) * 8)];
        acc[dt] = __builtin_amdgcn_mfma_f32_32x32x16_bf16(pc.v, vb, acc[dt], 0, 0, 0);
      }
    }
  }

  float inv = 1.0f / l_s;
  #pragma unroll
  for (int reg = 0; reg < 16; reg++){
    int cr = (reg & 3) + 8 * (reg >> 2) + 4 * hi;
    float li = __shfl(inv, cr);
    int row = qrow0 + cr;
    #pragma unroll
    for (int dt = 0; dt < 4; dt++)
      out[(size_t)(b * SEQ + row) * DIM + h * DHEAD + dt * 32 + l31] = f2bf(acc[dt][reg] * li);
  }
}

// ---------------- launch ----------------
extern "C" void kernel_launch(void* const* d_in, const int* in_sizes, int n_in,
                              void* d_out, int out_size, void* d_ws, size_t ws_size,
                              hipStream_t stream) {
  (void)in_sizes; (void)n_in; (void)out_size; (void)ws_size;
  const float* tokens = (const float*)d_in[0];
  const float* normw  = (const float*)d_in[1];
  const float* wq     = (const float*)d_in[2];
  const float* wkv    = (const float*)d_in[3];
  const float* wout   = (const float*)d_in[4];
  float* outp = (float*)d_out;
  char* ws = (char*)d_ws;

  short* x     = (short*)(ws + 0);                    // 8192*2048*2   = 33554432
  short* wqt   = (short*)(ws + 33554432);             // 2048*2048*2   = 8388608
  short* wkvt  = (short*)(ws + 41943040);             // 4096*2048*2   = 16777216
  short* woutt = (short*)(ws + 58720256);             // 2048*2048*2   = 8388608
  short* qb    = (short*)(ws + 67108864);             // 8192*2048*2   = 33554432 (also attn out)
  short* kvb   = (short*)(ws + 100663296);            // 8192*4096*2   = 67108864 (K half used)
  short* vtb   = (short*)(ws + 167772160);            // 64*128*2048*2 = 33554432  (end 201326592)

  rmsnorm_cast_k<<<dim3(MROWS), dim3(256), 0, stream>>>(tokens, normw, x);
  wtrans_k<<<dim3(2048/64, 2048/64), dim3(256), 0, stream>>>(wq,   wqt,   2048, 2048);
  wtrans_k<<<dim3(4096/64, 2048/64), dim3(256), 0, stream>>>(wkv,  wkvt,  2048, 4096);
  wtrans_k<<<dim3(2048/64, 2048/64), dim3(256), 0, stream>>>(wout, woutt, 2048, 2048);
  gemm256_k<short,0><<<dim3((MROWS/256)*(2048/256)), dim3(512), 0, stream>>>(x, wqt,  qb,  nullptr, MROWS, 2048, 2048, 3);
  gemm256_k<short,1><<<dim3((MROWS/256)*(4096/256)), dim3(512), 0, stream>>>(x, wkvt, kvb, vtb,     MROWS, 4096, 2048, 4);
  attn_k<<<dim3(SEQ/128 * BATCH*HEADS), dim3(256), 0, stream>>>(qb, kvb, vtb, qb);
  gemm256_k<float,0><<<dim3((MROWS/256)*(2048/256)), dim3(512), 0, stream>>>(qb, woutt, outp, nullptr, MROWS, 2048, 2048, 3);
}